// Round 7
// baseline (515.552 us; speedup 1.0000x reference)
//
#include <hip/hip_runtime.h>
#include <math.h>

#define N_ROWS 262144
#define K_CODES 1024
#define D_DIM 64

typedef __attribute__((ext_vector_type(8))) short short8;
typedef __attribute__((ext_vector_type(4))) float f32x4;
typedef unsigned short ushortT;
typedef unsigned int uintT;

// bf16 round-to-nearest-even of a finite fp32, returned as raw bf16 bits.
__device__ inline uintT bf16_rne_bits(float v) {
    uintT u = __float_as_uint(v);
    return (u + 0x7FFFu + ((u >> 16) & 1u)) >> 16;
}

// ---------------------------------------------------------------------------
// Prep: c_sq (EXACT same accumulation order as the validated kernel),
// codebook bf16 hi/lo split.
// ---------------------------------------------------------------------------
__global__ __launch_bounds__(64) void prep_kernel(const float* __restrict__ cb,
                                                  ushortT* __restrict__ cbh,
                                                  ushortT* __restrict__ cbl,
                                                  float* __restrict__ c_sq) {
    int k = blockIdx.x * 64 + threadIdx.x;
    if (k >= K_CODES) return;
    const float4* row = (const float4*)(cb + (size_t)k * D_DIM);
    float s = 0.0f;
#pragma unroll
    for (int j = 0; j < D_DIM / 4; ++j) {
        float4 v = row[j];
        s = fmaf(v.x, v.x, s);
        s = fmaf(v.y, v.y, s);
        s = fmaf(v.z, v.z, s);
        s = fmaf(v.w, v.w, s);
        float e[4] = {v.x, v.y, v.z, v.w};
#pragma unroll
        for (int q = 0; q < 4; ++q) {
            int d = 4 * j + q;
            uintT hb = bf16_rne_bits(e[q]);
            float hif = __uint_as_float(hb << 16);
            uintT lb = bf16_rne_bits(e[q] - hif);
            cbh[(size_t)k * D_DIM + d] = (ushortT)hb;
            cbl[(size_t)k * D_DIM + d] = (ushortT)lb;
        }
    }
    c_sq[k] = s;
}

// ---------------------------------------------------------------------------
// Coarse kernel, round 7:
//  - LDS DOUBLE-BUFFER, ONE barrier/round (was 2): compute from buf[r&1]
//    while ds_writing buf[(r+1)&1] whose data was loaded a full round ago
//    (the vmcnt drain before ds_write has ~700cy slack). Removes the
//    staging-visibility barrier convoy that kept both pipes <25% busy.
//  - INLINE exact rescan of flagged rows (verbatim validated fallback
//    arithmetic) -> fallback kernel + worklist deleted. The ~190us constant
//    (total - coarse) across all rounds is attributed to fallback_kernel.
//  - COALESCED epilogue: lanes write contiguous 16B chunks (round-6 pattern
//    was 16B at 128B stride -> 455MB WRITE_SIZE, ~3.5x amplification).
//  - Main-loop numerics identical to round 6 (absmax 0.0).
// ---------------------------------------------------------------------------
__global__ __launch_bounds__(256, 4) void coarse_kernel(
        const float* __restrict__ x_all, const float* __restrict__ cb,
        const ushortT* __restrict__ cbh, const ushortT* __restrict__ cbl,
        const float* __restrict__ c_sq_g,
        float* __restrict__ out_idx, float* __restrict__ out_res,
        float* __restrict__ out_emb) {
    __shared__ __align__(16) ushortT stage[2][8192];  // 2 x 16 KB: 64 codes hi+lo
    __shared__ float csq_s[K_CODES];                  // 4 KB
    __shared__ float xsq_s[128];
    __shared__ int   idx_s[128];

    const int t  = threadIdx.x;
    const int w  = t >> 6;          // wave 0..3
    const int L  = t & 63;          // lane
    const int q  = L >> 4;          // quad 0..3
    const int n  = L & 15;          // class / col
    const int rowbase = blockIdx.x * 128 + w * 32;

    // ---- c_sq -> LDS (once; visible after prologue barrier)
    ((float4*)csq_s)[t] = ((const float4*)c_sq_g)[t];

    // ---- load + convert A fragments (x rows), x_sq (validated code) ----
    short8 ah[2][2], al[2][2];
#pragma unroll
    for (int s = 0; s < 2; ++s) {
        float part = 0.0f;
#pragma unroll
        for (int kt = 0; kt < 2; ++kt) {
            const float4* p = (const float4*)(x_all +
                (size_t)(rowbase + s * 16 + n) * D_DIM + kt * 32 + q * 8);
            float4 v0 = p[0], v1 = p[1];
            float e[8] = {v0.x, v0.y, v0.z, v0.w, v1.x, v1.y, v1.z, v1.w};
#pragma unroll
            for (int j = 0; j < 8; ++j) {
                part = fmaf(e[j], e[j], part);
                uintT hb = bf16_rne_bits(e[j]);
                float hif = __uint_as_float(hb << 16);
                uintT lb = bf16_rne_bits(e[j] - hif);
                ah[s][kt][j] = (short)hb;
                al[s][kt][j] = (short)lb;
            }
        }
        part += __shfl_xor(part, 16);
        part += __shfl_xor(part, 32);
        if (q == 0) xsq_s[w * 32 + s * 16 + n] = part;
    }

    // ---- staging helpers: round rr = 64 codes (4 tiles), hi+lo = 16 KB ----
    auto fetch = [&](int rr, uint4* pre) {
#pragma unroll
        for (int i = 0; i < 4; ++i) {
            int c = i * 256 + t;                 // 16B chunk 0..1023
            int tile = c >> 8, inner = c & 255;
            int hilo = inner >> 7, cc = inner & 127;
            int kt = cc >> 6, LL = cc & 63;
            const ushortT* src = hilo ? cbl : cbh;
            size_t elem = (size_t)(rr * 64 + tile * 16 + (LL & 15)) * D_DIM +
                          kt * 32 + (LL >> 4) * 8;
            pre[i] = *(const uint4*)(src + elem);
        }
    };
    auto store_stage = [&](int b, const uint4* pre) {
#pragma unroll
        for (int i = 0; i < 4; ++i)
            *(uint4*)(&stage[b][(size_t)(i * 256 + t) * 8]) = pre[i];
    };

    // ---- prologue: buf0 <- round 0; pre <- round 1 ----
    uint4 pre[4];
    fetch(0, pre);
    store_stage(0, pre);
    fetch(1, pre);

    // ---- packed trackers (validated): INT_MIN sentinel ----
    int m1p[2][4], m2p[2][4];
#pragma unroll
    for (int s = 0; s < 2; ++s)
#pragma unroll
        for (int j = 0; j < 4; ++j) { m1p[s][j] = (int)0x80000000; m2p[s][j] = (int)0x80000000; }

    __syncthreads();   // buf0 + csq_s visible

    // ---- main loop: 16 rounds x 4 tiles, ONE barrier per round ----
    for (int r = 0; r < 16; ++r) {
        const ushortT* sb = stage[r & 1];
#pragma unroll
        for (int tl = 0; tl < 4; ++tl) {
            const int tb = tl * 2048;        // ushort offset of tile
            short8 bh0 = *(const short8*)(sb + tb +    0 + L * 8);
            short8 bh1 = *(const short8*)(sb + tb +  512 + L * 8);
            short8 bl0 = *(const short8*)(sb + tb + 1024 + L * 8);
            short8 bl1 = *(const short8*)(sb + tb + 1536 + L * 8);

            // 4 independent chains of depth 3 (validated round 6)
            f32x4 p0 = {0.f,0.f,0.f,0.f}, q0 = {0.f,0.f,0.f,0.f};
            f32x4 p1 = {0.f,0.f,0.f,0.f}, q1 = {0.f,0.f,0.f,0.f};
            p0 = __builtin_amdgcn_mfma_f32_16x16x32_bf16(ah[0][0], bh0, p0, 0, 0, 0);
            p1 = __builtin_amdgcn_mfma_f32_16x16x32_bf16(ah[1][0], bh0, p1, 0, 0, 0);
            q0 = __builtin_amdgcn_mfma_f32_16x16x32_bf16(ah[0][1], bl1, q0, 0, 0, 0);
            q1 = __builtin_amdgcn_mfma_f32_16x16x32_bf16(ah[1][1], bl1, q1, 0, 0, 0);
            p0 = __builtin_amdgcn_mfma_f32_16x16x32_bf16(ah[0][1], bh1, p0, 0, 0, 0);
            p1 = __builtin_amdgcn_mfma_f32_16x16x32_bf16(ah[1][1], bh1, p1, 0, 0, 0);
            q0 = __builtin_amdgcn_mfma_f32_16x16x32_bf16(al[0][0], bh0, q0, 0, 0, 0);
            q1 = __builtin_amdgcn_mfma_f32_16x16x32_bf16(al[1][0], bh0, q1, 0, 0, 0);
            p0 = __builtin_amdgcn_mfma_f32_16x16x32_bf16(ah[0][0], bl0, p0, 0, 0, 0);
            p1 = __builtin_amdgcn_mfma_f32_16x16x32_bf16(ah[1][0], bl0, p1, 0, 0, 0);
            q0 = __builtin_amdgcn_mfma_f32_16x16x32_bf16(al[0][1], bh1, q0, 0, 0, 0);
            q1 = __builtin_amdgcn_mfma_f32_16x16x32_bf16(al[1][1], bh1, q1, 0, 0, 0);
            f32x4 s0 = p0 + q0;
            f32x4 s1 = p1 + q1;

            int tg = r * 4 + tl;             // global tile 0..63
            float cv = csq_s[tg * 16 + n];
            uintT kcp = (uintT)(63 - tg);    // complement -> packed max == first occurrence
#pragma unroll
            for (int j = 0; j < 4; ++j) {
                float v0 = fmaf(2.0f, s0[j], -cv);
                int u0 = (int)((__float_as_uint(v0) & 0xFFFFFFC0u) | kcp);
                m2p[0][j] = max(m2p[0][j], min(m1p[0][j], u0));
                m1p[0][j] = max(m1p[0][j], u0);
                float v1 = fmaf(2.0f, s1[j], -cv);
                int u1 = (int)((__float_as_uint(v1) & 0xFFFFFFC0u) | kcp);
                m2p[1][j] = max(m2p[1][j], min(m1p[1][j], u1));
                m1p[1][j] = max(m1p[1][j], u1);
            }
        }
        if (r < 15) {
            store_stage((r + 1) & 1, pre);   // data loaded a full round ago
            if (r < 14) fetch(r + 2, pre);   // issue next loads after the drain
        }
        __syncthreads();
    }

    // ---- decode + butterfly reduce across the 16 classes (max-space) ----
#pragma unroll
    for (int s = 0; s < 2; ++s)
#pragma unroll
        for (int j = 0; j < 4; ++j) {
            int p1i = m1p[s][j], p2i = m2p[s][j];
            float a1 = __uint_as_float((uintT)p1i & 0xFFFFFFC0u);
            float a2 = __uint_as_float((uintT)p2i & 0xFFFFFFC0u);
            int ai = ((63 - (p1i & 63)) << 4) | n;   // idx = tile*16 + n
#pragma unroll
            for (int msk = 1; msk < 16; msk <<= 1) {
                float o1 = __shfl_xor(a1, msk);
                float o2 = __shfl_xor(a2, msk);
                int oi = __shfl_xor(ai, msk);
                float nm2 = fmaxf(fminf(a1, o1), fmaxf(a2, o2));
                bool take = (o1 > a1) || (o1 == a1 && oi < ai);
                a1 = take ? o1 : a1;
                ai = take ? oi : ai;
                a2 = nm2;
            }
            if (n == 0) {
                int rl = w * 32 + s * 16 + q * 4 + j;
                float xsq = xsq_s[rl];
                float xn = sqrtf(xsq);
                // 2*margin (validated: 8e-5*xn + 4e-4) + 2*quant (2^-12)
                float thr = fmaf(8.0e-5f, xn, 6.44140625e-4f);
                bool fb = ((a1 - a2) <= thr) || (a2 < 0.0f) || (xsq > 170.0f);
                idx_s[rl] = ai | (fb ? (1 << 30) : 0);
            }
        }
    __syncthreads();

    // ---- outputs for CONFIDENT rows (coalesced: consecutive lanes write
    //      consecutive 16B chunks; round-6 strided pattern caused 3.5x
    //      HBM write amplification) ----
    if (t < 128) {
        int e = idx_s[t];
        if (!(e >> 30)) out_idx[blockIdx.x * 128 + t] = (float)(e & 0x3FFFFFFF);
    }
#pragma unroll
    for (int c2 = 0; c2 < 8; ++c2) {
        int f = c2 * 256 + t;                // float4 index in block's 128x64 region
        int lr = f >> 4;                     // local row
        int e = idx_s[lr];
        if (e >> 30) continue;               // flagged: rescan writes it
        int id = e & 0x3FFFFFFF;
        size_t row = (size_t)blockIdx.x * 128 + lr;
        int el = f & 15;                     // float4 slot within row
        float4 xv = ((const float4*)(x_all + row * D_DIM))[el];
        float4 cv = ((const float4*)(cb + (size_t)id * D_DIM))[el];
        float4 rv;
        rv.x = xv.x - cv.x; rv.y = xv.y - cv.y;
        rv.z = xv.z - cv.z; rv.w = xv.w - cv.w;
        ((float4*)(out_res + row * D_DIM))[el] = rv;
        ((float4*)(out_emb + row * D_DIM))[el] = cv;
    }

    // ---- INLINE exact rescan of this wave's flagged rows (verbatim
    //      validated fallback arithmetic; csq_s holds identical values) ----
    for (int rr = 0; rr < 32; ++rr) {
        int lr = w * 32 + rr;
        int e = idx_s[lr];
        if (!(e >> 30)) continue;            // wave-uniform branch
        size_t row = (size_t)blockIdx.x * 128 + lr;

        float x[D_DIM];
        const float4* xr = (const float4*)(x_all + row * D_DIM);
#pragma unroll
        for (int j = 0; j < D_DIM / 4; ++j) {
            float4 v = xr[j];
            x[4 * j + 0] = v.x; x[4 * j + 1] = v.y;
            x[4 * j + 2] = v.z; x[4 * j + 3] = v.w;
        }
        float x_sq = 0.0f;
#pragma unroll
        for (int d = 0; d < D_DIM; ++d) x_sq = fmaf(x[d], x[d], x_sq);

        float best = INFINITY;
        int bidx = 0x7FFFFFFF;
        for (int kk = 0; kk < 16; ++kk) {
            int k = kk * 64 + L;
            const float* c0 = cb + (size_t)k * D_DIM;
            float a00 = 0.f, a01 = 0.f, a02 = 0.f, a03 = 0.f;
#pragma unroll
            for (int j = 0; j < 4; ++j) {
                float4 v0 = *(const float4*)(c0 + 16 * j + 0);
                float4 v1 = *(const float4*)(c0 + 16 * j + 4);
                float4 v2 = *(const float4*)(c0 + 16 * j + 8);
                float4 v3 = *(const float4*)(c0 + 16 * j + 12);
                float* a = (j == 0) ? &a00 : (j == 1) ? &a01 : (j == 2) ? &a02 : &a03;
                float acc = *a;
                acc = fmaf(x[16 * j + 0],  v0.x, acc);
                acc = fmaf(x[16 * j + 1],  v0.y, acc);
                acc = fmaf(x[16 * j + 2],  v0.z, acc);
                acc = fmaf(x[16 * j + 3],  v0.w, acc);
                acc = fmaf(x[16 * j + 4],  v1.x, acc);
                acc = fmaf(x[16 * j + 5],  v1.y, acc);
                acc = fmaf(x[16 * j + 6],  v1.z, acc);
                acc = fmaf(x[16 * j + 7],  v1.w, acc);
                acc = fmaf(x[16 * j + 8],  v2.x, acc);
                acc = fmaf(x[16 * j + 9],  v2.y, acc);
                acc = fmaf(x[16 * j + 10], v2.z, acc);
                acc = fmaf(x[16 * j + 11], v2.w, acc);
                acc = fmaf(x[16 * j + 12], v3.x, acc);
                acc = fmaf(x[16 * j + 13], v3.y, acc);
                acc = fmaf(x[16 * j + 14], v3.z, acc);
                acc = fmaf(x[16 * j + 15], v3.w, acc);
                *a = acc;
            }
            float dot = (a00 + a01) + (a02 + a03);
            float d = (x_sq - 2.0f * dot) + csq_s[k];
            if (d < best) { best = d; bidx = k; }
        }

        // cross-lane argmin, smaller-index tie-break => global first-occurrence
#pragma unroll
        for (int msk = 1; msk < 64; msk <<= 1) {
            float ob = __shfl_xor(best, msk);
            int oi = __shfl_xor(bidx, msk);
            bool take = (ob < best) || (ob == best && oi < bidx);
            best = take ? ob : best;
            bidx = take ? oi : bidx;
        }

        if (L < 16) {
            const float4* cbest = (const float4*)(cb + (size_t)bidx * D_DIM);
            float4 c = cbest[L];
            float4 v;
            v.x = x[4 * L + 0] - c.x; v.y = x[4 * L + 1] - c.y;
            v.z = x[4 * L + 2] - c.z; v.w = x[4 * L + 3] - c.w;
            ((float4*)(out_res + row * D_DIM))[L] = v;
            ((float4*)(out_emb + row * D_DIM))[L] = c;
            if (L == 0) out_idx[row] = (float)bidx;
        }
    }
}

extern "C" void kernel_launch(void* const* d_in, const int* in_sizes, int n_in,
                              void* d_out, int out_size, void* d_ws, size_t ws_size,
                              hipStream_t stream) {
    const float* x  = (const float*)d_in[0];
    const float* cb = (const float*)d_in[1];

    char* base = (char*)d_ws;
    ushortT* cbh = (ushortT*)base;                         // 128 KB
    ushortT* cbl = (ushortT*)(base + 131072);              // 128 KB
    float*   csq = (float*)(base + 262144);                // 4 KB

    float* out   = (float*)d_out;
    float* o_idx = out;
    float* o_res = out + (size_t)N_ROWS;
    float* o_emb = o_res + (size_t)N_ROWS * D_DIM;

    prep_kernel<<<16, 64, 0, stream>>>(cb, cbh, cbl, csq);
    coarse_kernel<<<N_ROWS / 128, 256, 0, stream>>>(x, cb, cbh, cbl, csq,
                                                    o_idx, o_res, o_emb);
}